// Round 6
// baseline (378.941 us; speedup 1.0000x reference)
//
#include <hip/hip_runtime.h>
#include <stdint.h>

// Sampler: B=128 rows, V=128000 vocab, K=20. Single fused kernel.
// Outputs (float32, concat): sampled[B], topk_logprobs[B*K], topk_indices[B*K].
//
// k1_fused (B*nsplit blocks x 256): register-pipelined float4 stream
//     (exp2-sum, gumbel argmax w/ cheap screen, TAU=3.0 top-K candidates),
//     then last-block-per-row inline finalize (threadfence + device atomic
//     arrival counter; agent-scope atomic loads of peer partials) -- removes
//     the k2 launch (+gap) entirely and overlaps finalize with streaming.

#define KMAX 20
#define SAMPLING_EPS 1e-5f
#define TAU 3.0f
#define CPB 64    // candidate slots per k1 block
#define LOG2E 1.44269504f
#define SMARGIN 3e-4f   // screen margin, log2 units (covers all fp rounding)

static __device__ __forceinline__ float fexp2(float x) {
#if __has_builtin(__builtin_amdgcn_exp2f)
    return __builtin_amdgcn_exp2f(x);
#else
    return exp2f(x);
#endif
}

static __device__ __forceinline__ unsigned int ord32(float v) {
    unsigned int u = __float_as_uint(v);
    return u ^ ((unsigned int)((int)u >> 31) | 0x80000000u);
}
static __device__ __forceinline__ float unord32(unsigned int x) {
    unsigned int u = (x & 0x80000000u) ? (x ^ 0x80000000u) : ~x;
    return __uint_as_float(u);
}
static __device__ __forceinline__ unsigned long long shflxor64(unsigned long long v, int off) {
    int lo = __shfl_xor((int)(unsigned int)v, off, 64);
    int hi = __shfl_xor((int)(unsigned int)(v >> 32), off, 64);
    return ((unsigned long long)(unsigned int)hi << 32) | (unsigned int)lo;
}
// agent-scope (device) atomic loads: bypass stale per-XCD caches (G16)
static __device__ __forceinline__ unsigned int aload_u32(const unsigned int* p) {
    return __hip_atomic_load(p, __ATOMIC_RELAXED, __HIP_MEMORY_SCOPE_AGENT);
}
static __device__ __forceinline__ unsigned long long aload_u64(const unsigned long long* p) {
    return __hip_atomic_load(p, __ATOMIC_RELAXED, __HIP_MEMORY_SCOPE_AGENT);
}

// Gumbel exact eval: g = x*inv_t - log(-log u). Winner's u is ~1, where
// log1pf on the Sterbenz-exact (1-u) keeps relative accuracy.
static __device__ __forceinline__ float gumbel_exact(float x, float inv_t, float uu, float wm) {
    const float q = (uu > 0.984375f) ? -log1pf(-wm) : -__logf(uu);
    return x * inv_t - __logf(q);
}

// Provable upper bound of g*log2e: -log2(-log u) <= -log2(1-u) <= 127 - bits(1-u)*2^-23
static __device__ __forceinline__ float gub_bound(float a, float uu) {
    return fmaf((float)__float_as_uint(1.0f - uu), -0x1p-23f, 127.0f + a);
}

__global__ __launch_bounds__(256, 4) void k1_fused(
        const float* __restrict__ logits, const float* __restrict__ u,
        const float* __restrict__ temp,
        unsigned int* wrec,      // per-wave {s, gval, gcol, pad}  (cross-block comm)
        unsigned int* cntbuf,    // per-block raw candidate count
        uint2* candbuf,          // per-block CPB {val_bits, col}
        unsigned int* rowcnt,    // per-row arrival counter (memset to 0 pre-launch)
        float* __restrict__ out,
        int B, int V, int K, int nsplit) {
    __shared__ int cnt;
    __shared__ uint2 cand[CPB];
    __shared__ unsigned long long kbuf[512];
    __shared__ int lastflag;
    const int b = blockIdx.x;
    const int t = threadIdx.x;
    const int lane = t & 63;
    const int w = t >> 6;
    if (t == 0) cnt = 0;
    __syncthreads();

    // ---- block -> (row, split) remap: mixes greedy(r%4==0)/non-greedy rows
    // across any plausible dispatch stride. Bijective (see round-1 notes).
    const int nrows = gridDim.x / nsplit;
    const int mb = b % nrows;
    const int sp = b / nrows;
    int r = (mb * 61 + (sp >> 1)) % nrows;
    if ((nrows & (nrows - 1)) == 0) r ^= (r >> 4);
    const int slot = r * nsplit + sp;         // storage slot

    const float traw = temp[r];
    const bool greedy = traw < SAMPLING_EPS;
    const float inv_t = greedy ? 1.0f : (1.0f / traw);
    const float it2 = inv_t * LOG2E;          // scaled-arg in log2 units

    const int nf4 = V >> 2;
    const int per = (nf4 + nsplit - 1) / nsplit;
    const int f0 = sp * per;
    const int f1 = min(f0 + per, nf4);

    const float4* __restrict__ l4 = (const float4*)(logits + (size_t)r * V);
    const float4* __restrict__ u4 = (const float4*)(u + (size_t)r * V);

    float s0 = 0.0f, s1 = 0.0f, s2 = 0.0f, s3 = 0.0f;
    float gv = -INFINITY;
    int gcol = 0;
    const float4 z4 = make_float4(0.f, 0.f, 0.f, 0.f);

#define PUSH(xv, cc) do { \
        const int pi_ = atomicAdd(&cnt, 1); \
        if (pi_ < CPB) cand[pi_] = make_uint2(__float_as_uint(xv), (unsigned)(cc)); \
    } while (0)

    if (greedy) {
        int f = f0 + t;
        bool m = (f + 256 < f1);
        float4 ca = z4, cb = z4;
        if (m) { ca = l4[f]; cb = l4[f + 256]; }
        while (m) {
            const int fn = f + 512;
            const bool mn = (fn + 256 < f1);
            float4 na = z4, nb = z4;
            if (mn) { na = l4[fn]; nb = l4[fn + 256]; }
            s0 += fexp2(ca.x * it2); s1 += fexp2(ca.y * it2);
            s2 += fexp2(ca.z * it2); s3 += fexp2(ca.w * it2);
            s0 += fexp2(cb.x * it2); s1 += fexp2(cb.y * it2);
            s2 += fexp2(cb.z * it2); s3 += fexp2(cb.w * it2);
            const float xm = fmaxf(fmaxf(fmaxf(ca.x, ca.y), fmaxf(ca.z, ca.w)),
                                   fmaxf(fmaxf(cb.x, cb.y), fmaxf(cb.z, cb.w)));
            if (xm >= TAU) {
                const int c0 = f << 2, c1 = (f + 256) << 2;
                if (ca.x >= TAU) PUSH(ca.x, c0);
                if (ca.y >= TAU) PUSH(ca.y, c0 + 1);
                if (ca.z >= TAU) PUSH(ca.z, c0 + 2);
                if (ca.w >= TAU) PUSH(ca.w, c0 + 3);
                if (cb.x >= TAU) PUSH(cb.x, c1);
                if (cb.y >= TAU) PUSH(cb.y, c1 + 1);
                if (cb.z >= TAU) PUSH(cb.z, c1 + 2);
                if (cb.w >= TAU) PUSH(cb.w, c1 + 3);
            }
            f = fn; m = mn; ca = na; cb = nb;
        }
        for (; f < f1; f += 256) {
            const float4 la = l4[f];
            s0 += fexp2(la.x * it2); s1 += fexp2(la.y * it2);
            s2 += fexp2(la.z * it2); s3 += fexp2(la.w * it2);
            const float xm = fmaxf(fmaxf(la.x, la.y), fmaxf(la.z, la.w));
            if (xm >= TAU) {
                const int c0 = f << 2;
                if (la.x >= TAU) PUSH(la.x, c0);
                if (la.y >= TAU) PUSH(la.y, c0 + 1);
                if (la.z >= TAU) PUSH(la.z, c0 + 2);
                if (la.w >= TAU) PUSH(la.w, c0 + 3);
            }
        }
    } else {
        const int fp = f0 + t;
        float4 la0 = z4, ua0 = z4;
        const bool hasp = fp < f1;
        if (hasp) { la0 = l4[fp]; ua0 = u4[fp]; }
        int f = fp + 256;
        bool m = (f + 256 < f1);
        float4 ca = z4, cb = z4, cua = z4, cub = z4;
        if (m) { ca = l4[f]; cb = l4[f + 256]; cua = u4[f]; cub = u4[f + 256]; }

        if (hasp) {
            const int c0 = fp << 2;
            s0 += fexp2(la0.x * it2); s1 += fexp2(la0.y * it2);
            s2 += fexp2(la0.z * it2); s3 += fexp2(la0.w * it2);
            { const float g = gumbel_exact(la0.x, inv_t, ua0.x, 1.0f - ua0.x);
              if (g > gv) { gv = g; gcol = c0; } }
            { const float g = gumbel_exact(la0.y, inv_t, ua0.y, 1.0f - ua0.y);
              if (g > gv) { gv = g; gcol = c0 + 1; } }
            { const float g = gumbel_exact(la0.z, inv_t, ua0.z, 1.0f - ua0.z);
              if (g > gv) { gv = g; gcol = c0 + 2; } }
            { const float g = gumbel_exact(la0.w, inv_t, ua0.w, 1.0f - ua0.w);
              if (g > gv) { gv = g; gcol = c0 + 3; } }
            const float xm = fmaxf(fmaxf(la0.x, la0.y), fmaxf(la0.z, la0.w));
            if (xm >= TAU) {
                if (la0.x >= TAU) PUSH(la0.x, c0);
                if (la0.y >= TAU) PUSH(la0.y, c0 + 1);
                if (la0.z >= TAU) PUSH(la0.z, c0 + 2);
                if (la0.w >= TAU) PUSH(la0.w, c0 + 3);
            }
        }
        float gmax = gv;
        #pragma unroll
        for (int off = 1; off < 64; off <<= 1) gmax = fmaxf(gmax, __shfl_xor(gmax, off, 64));
        float gvs2 = fmaf(gmax, LOG2E, -SMARGIN);

#define EX(gj, xv, uu, cc) \
        if ((gj) > gvs2) { \
            const float wm_ = 1.0f - (uu); \
            const float ge_ = gumbel_exact(xv, inv_t, uu, wm_); \
            if (ge_ > gv) { gv = ge_; gcol = (cc); gvs2 = fmaf(ge_, LOG2E, -SMARGIN); } \
        }

        while (m) {
            const int fn = f + 512;
            const bool mn = (fn + 256 < f1);
            float4 na = z4, nb = z4, nua = z4, nub = z4;
            if (mn) { na = l4[fn]; nb = l4[fn + 256]; nua = u4[fn]; nub = u4[fn + 256]; }

            const float a0 = ca.x * it2, a1 = ca.y * it2, a2 = ca.z * it2, a3 = ca.w * it2;
            const float a4 = cb.x * it2, a5 = cb.y * it2, a6 = cb.z * it2, a7 = cb.w * it2;
            s0 += fexp2(a0); s1 += fexp2(a1); s2 += fexp2(a2); s3 += fexp2(a3);
            s0 += fexp2(a4); s1 += fexp2(a5); s2 += fexp2(a6); s3 += fexp2(a7);
            const float g0 = gub_bound(a0, cua.x), g1 = gub_bound(a1, cua.y);
            const float g2 = gub_bound(a2, cua.z), g3 = gub_bound(a3, cua.w);
            const float g4 = gub_bound(a4, cub.x), g5 = gub_bound(a5, cub.y);
            const float g6 = gub_bound(a6, cub.z), g7 = gub_bound(a7, cub.w);
            const float gm = fmaxf(fmaxf(fmaxf(g0, g1), fmaxf(g2, g3)),
                                   fmaxf(fmaxf(g4, g5), fmaxf(g6, g7)));
            if (gm > gvs2) {
                const int c0 = f << 2, c1 = (f + 256) << 2;
                EX(g0, ca.x, cua.x, c0)
                EX(g1, ca.y, cua.y, c0 + 1)
                EX(g2, ca.z, cua.z, c0 + 2)
                EX(g3, ca.w, cua.w, c0 + 3)
                EX(g4, cb.x, cub.x, c1)
                EX(g5, cb.y, cub.y, c1 + 1)
                EX(g6, cb.z, cub.z, c1 + 2)
                EX(g7, cb.w, cub.w, c1 + 3)
            }
            const float xm = fmaxf(fmaxf(fmaxf(ca.x, ca.y), fmaxf(ca.z, ca.w)),
                                   fmaxf(fmaxf(cb.x, cb.y), fmaxf(cb.z, cb.w)));
            if (xm >= TAU) {
                const int c0 = f << 2, c1 = (f + 256) << 2;
                if (ca.x >= TAU) PUSH(ca.x, c0);
                if (ca.y >= TAU) PUSH(ca.y, c0 + 1);
                if (ca.z >= TAU) PUSH(ca.z, c0 + 2);
                if (ca.w >= TAU) PUSH(ca.w, c0 + 3);
                if (cb.x >= TAU) PUSH(cb.x, c1);
                if (cb.y >= TAU) PUSH(cb.y, c1 + 1);
                if (cb.z >= TAU) PUSH(cb.z, c1 + 2);
                if (cb.w >= TAU) PUSH(cb.w, c1 + 3);
            }
            f = fn; m = mn;
            ca = na; cb = nb; cua = nua; cub = nub;
        }
        for (; f < f1; f += 256) {
            const float4 la = l4[f];
            const float4 ua = u4[f];
            const float a0 = la.x * it2, a1 = la.y * it2, a2 = la.z * it2, a3 = la.w * it2;
            s0 += fexp2(a0); s1 += fexp2(a1); s2 += fexp2(a2); s3 += fexp2(a3);
            const float g0 = gub_bound(a0, ua.x), g1 = gub_bound(a1, ua.y);
            const float g2 = gub_bound(a2, ua.z), g3 = gub_bound(a3, ua.w);
            const float gm = fmaxf(fmaxf(g0, g1), fmaxf(g2, g3));
            if (gm > gvs2) {
                const int c0 = f << 2;
                EX(g0, la.x, ua.x, c0)
                EX(g1, la.y, ua.y, c0 + 1)
                EX(g2, la.z, ua.z, c0 + 2)
                EX(g3, la.w, ua.w, c0 + 3)
            }
            const float xm = fmaxf(fmaxf(la.x, la.y), fmaxf(la.z, la.w));
            if (xm >= TAU) {
                const int c0 = f << 2;
                if (la.x >= TAU) PUSH(la.x, c0);
                if (la.y >= TAU) PUSH(la.y, c0 + 1);
                if (la.z >= TAU) PUSH(la.z, c0 + 2);
                if (la.w >= TAU) PUSH(la.w, c0 + 3);
            }
        }
#undef EX
    }
#undef PUSH

    // wave reductions: s sum, gumbel key max (val desc, col asc)
    float s = (s0 + s1) + (s2 + s3);
    #pragma unroll
    for (int off = 1; off < 64; off <<= 1) s += __shfl_xor(s, off, 64);
    unsigned long long gk = greedy ? 0ull
        : (((unsigned long long)ord32(gv) << 32) | (unsigned int)~(unsigned int)gcol);
    #pragma unroll
    for (int off = 1; off < 64; off <<= 1) {
        const unsigned long long o = shflxor64(gk, off);
        gk = (o > gk) ? o : gk;
    }
    if (lane == 0) {
        unsigned int* rp = wrec + (size_t)(slot * 4 + w) * 4;
        rp[0] = __float_as_uint(s);
        rp[1] = __float_as_uint(unord32((unsigned int)(gk >> 32)));
        rp[2] = ~(unsigned int)gk;
    }
    __syncthreads();
    const int c = cnt;
    if (t == 0) cntbuf[slot] = (unsigned)c;
    if (t < min(c, CPB)) candbuf[(size_t)slot * CPB + t] = cand[t];

    // ================= last-block-per-row inline finalize =================
    __threadfence();                 // release: this thread's stores device-visible
    __syncthreads();                 // all threads' stores + fences done
    if (t == 0) {
        const unsigned int old = atomicAdd(&rowcnt[r], 1u);
        lastflag = (old == (unsigned)(nsplit - 1)) ? 1 : 0;
    }
    __syncthreads();
    if (!lastflag || w != 0) return; // only wave 0 of the row-final block continues
    __threadfence();                 // acquire side

    const int NW = nsplit * 4;
    const float tt = greedy ? 1.0f : traw;

    // merge per-wave records (agent-scope loads)
    float fs = 0.0f;
    unsigned long long fgk = 0ull;
    if (lane < NW) {
        const unsigned int* rp = wrec + (size_t)(r * NW + lane) * 4;
        const unsigned int a0 = aload_u32(rp + 0);
        const unsigned int a1 = aload_u32(rp + 1);
        const unsigned int a2 = aload_u32(rp + 2);
        fs = __uint_as_float(a0);
        fgk = ((unsigned long long)ord32(__uint_as_float(a1)) << 32) | (unsigned int)~a2;
    }
    #pragma unroll
    for (int off = 1; off < 64; off <<= 1) fs += __shfl_xor(fs, off, 64);
    #pragma unroll
    for (int off = 1; off < 64; off <<= 1) {
        const unsigned long long o = shflxor64(fgk, off);
        fgk = (o > fgk) ? o : fgk;
    }
    const float lS = logf(fs);

    // gather candidates
    const int cnt_raw = (lane < nsplit) ? (int)aload_u32(&cntbuf[r * nsplit + lane]) : 0;
    const int cntc = min(cnt_raw, CPB);
    const bool ovf = __ballot(cnt_raw > CPB) != 0ull;
    int incl = cntc;
    #pragma unroll
    for (int d = 1; d < 64; d <<= 1) {
        const int o = __shfl_up(incl, d, 64);
        if (lane >= d) incl += o;
    }
    const int T = __shfl(incl, 63, 64);
    const int off0 = incl - cntc;

    unsigned long long keys[8];
    #pragma unroll
    for (int jj = 0; jj < 8; ++jj) keys[jj] = 0ull;

    if (!ovf && T >= K && T <= 512) {
        if (lane < nsplit) {
            const unsigned long long* cb =
                (const unsigned long long*)(candbuf + (size_t)(r * nsplit + lane) * CPB);
            for (int i = 0; i < cntc; ++i) {
                const unsigned long long e = aload_u64(cb + i);   // lo=val_bits, hi=col
                const unsigned int vbits = (unsigned int)e;
                const unsigned int col   = (unsigned int)(e >> 32);
                kbuf[off0 + i] = ((unsigned long long)ord32(__uint_as_float(vbits)) << 32)
                               | (unsigned int)~col;
            }
        }
        __threadfence_block();   // LDS write->read ordering within the wave
        #pragma unroll
        for (int jj = 0; jj < 8; ++jj) {
            const int idx = lane + 64 * jj;
            if (idx < T) keys[jj] = kbuf[idx];
        }
    } else {
        // exact fallback: wave-cooperative top-K full rescan (insurance)
        unsigned long long mykey = ((unsigned long long)0x007FFFFFu) << 32;
        unsigned long long minkey = mykey;
        float vmin = -INFINITY;
        const float* lr = logits + (size_t)r * V;
        for (int base = 0; base < V; base += 64) {
            const int i = base + lane;
            const float x = (i < V) ? lr[i] : -INFINITY;
            unsigned long long cm = __ballot((i < V) && (x >= vmin));
            while (cm) {
                const int src = (int)__builtin_ctzll(cm);
                cm &= cm - 1;
                const float cv = __shfl(x, src, 64);
                const int cc = __shfl(i, src, 64);
                const unsigned long long ck =
                    ((unsigned long long)ord32(cv) << 32) | (unsigned int)~(unsigned int)cc;
                if (ck > minkey) {
                    const bool own = (lane < K) && (mykey == minkey);
                    const unsigned long long om = __ballot(own);
                    if (lane == (int)__builtin_ctzll(om)) mykey = ck;
                    unsigned long long mk = (lane < K) ? mykey : ~0ull;
                    #pragma unroll
                    for (int o2 = 1; o2 < 64; o2 <<= 1) {
                        const unsigned long long o = shflxor64(mk, o2);
                        mk = (o < mk) ? o : mk;
                    }
                    minkey = mk;
                    vmin = unord32((unsigned int)(mk >> 32));
                }
            }
        }
        keys[0] = (lane < K) ? mykey : 0ull;
    }

    float* out_s  = out;
    float* out_lp = out + B;
    float* out_ix = out + B + (size_t)B * K;

    unsigned int top1 = 0;
    for (int k = 0; k < K; ++k) {
        unsigned long long loc = keys[0];
        #pragma unroll
        for (int jj = 1; jj < 8; ++jj) loc = (keys[jj] > loc) ? keys[jj] : loc;
        #pragma unroll
        for (int off = 1; off < 64; off <<= 1) {
            const unsigned long long o = shflxor64(loc, off);
            loc = (o > loc) ? o : loc;
        }
        #pragma unroll
        for (int jj = 0; jj < 8; ++jj) if (keys[jj] == loc) keys[jj] = 0ull;
        if (lane == 0) {
            const unsigned int col = ~(unsigned int)loc;
            const float v = unord32((unsigned int)(loc >> 32));
            out_lp[(size_t)r * K + k] = v / tt - lS;   // IEEE div matches ref's scaled
            out_ix[(size_t)r * K + k] = (float)col;
            if (k == 0) top1 = col;
        }
    }
    if (lane == 0) {
        out_s[r] = (float)(greedy ? top1 : (~(unsigned int)fgk));
    }
}

extern "C" void kernel_launch(void* const* d_in, const int* in_sizes, int n_in,
                              void* d_out, int out_size, void* d_ws, size_t ws_size,
                              hipStream_t stream) {
    const float* logits = (const float*)d_in[0];
    const float* temp   = (const float*)d_in[1];
    const float* u      = (const float*)d_in[2];
    const int B = in_sizes[1];
    const int V = in_sizes[0] / B;
    int K = (out_size - B) / (2 * B);
    if (K > KMAX) K = KMAX;
    if (K < 1) K = 1;

    // footprint per block: wrec 4 waves*16B + cnt 4B + cand CPB*8B = 580 B, + rowcnt B*4
    int nsplit = 16;
    while (nsplit > 1 && ((size_t)B * nsplit * 580 + (size_t)B * 4) > ws_size) nsplit >>= 1;
    const int blocks = B * nsplit;

    unsigned int* wrec   = (unsigned int*)d_ws;              // blocks*4 waves * 4 u32
    unsigned int* cntbuf = wrec + (size_t)blocks * 16;       // blocks u32
    uint2*        candbf = (uint2*)(cntbuf + blocks);        // blocks * CPB uint2
    unsigned int* rowcnt = (unsigned int*)(candbf + (size_t)blocks * CPB);  // B u32

    hipMemsetAsync((void*)rowcnt, 0, (size_t)B * sizeof(unsigned int), stream);

    k1_fused<<<dim3(blocks), dim3(256), 0, stream>>>(
        logits, u, temp, wrec, cntbuf, candbf, rowcnt, (float*)d_out, B, V, K, nsplit);
}

// Round 7
// 165.081 us; speedup vs baseline: 2.2955x; 2.2955x over previous
//
#include <hip/hip_runtime.h>
#include <stdint.h>

// Sampler: B=128 rows, V=128000 vocab, K=20. Single fused kernel.
// Outputs (float32, concat): sampled[B], topk_logprobs[B*K], topk_indices[B*K].
//
// k1_fused (B*nsplit blocks x 256): register-pipelined float4 stream
//     (exp2-sum, gumbel argmax w/ cheap screen, TAU=3.0 top-K candidates),
//     then last-block-per-row inline finalize. Cross-block protocol is
//     FENCE-FREE: all shared data moves through relaxed AGENT-scope atomics
//     (sc1 ops, individually coherent across XCDs) + s_waitcnt vmcnt(0)
//     before the arrival counter. NO __threadfence -- R6 measured the
//     agent release fence (buffer_wbl2 = full L2 tag-walk) at ~240 us for
//     2048 blocks. Removes the k2 launch (+gap) and overlaps finalize
//     with other rows' streaming.

#define KMAX 20
#define SAMPLING_EPS 1e-5f
#define TAU 3.0f
#define CPB 64    // candidate slots per k1 block
#define LOG2E 1.44269504f
#define SMARGIN 3e-4f   // screen margin, log2 units (covers all fp rounding)

static __device__ __forceinline__ float fexp2(float x) {
#if __has_builtin(__builtin_amdgcn_exp2f)
    return __builtin_amdgcn_exp2f(x);
#else
    return exp2f(x);
#endif
}

static __device__ __forceinline__ unsigned int ord32(float v) {
    unsigned int u = __float_as_uint(v);
    return u ^ ((unsigned int)((int)u >> 31) | 0x80000000u);
}
static __device__ __forceinline__ float unord32(unsigned int x) {
    unsigned int u = (x & 0x80000000u) ? (x ^ 0x80000000u) : ~x;
    return __uint_as_float(u);
}
static __device__ __forceinline__ unsigned long long shflxor64(unsigned long long v, int off) {
    int lo = __shfl_xor((int)(unsigned int)v, off, 64);
    int hi = __shfl_xor((int)(unsigned int)(v >> 32), off, 64);
    return ((unsigned long long)(unsigned int)hi << 32) | (unsigned int)lo;
}
// relaxed agent-scope atomics: individually coherent (sc1), NO fence emitted
static __device__ __forceinline__ unsigned int aload_u32(const unsigned int* p) {
    return __hip_atomic_load(p, __ATOMIC_RELAXED, __HIP_MEMORY_SCOPE_AGENT);
}
static __device__ __forceinline__ unsigned long long aload_u64(const unsigned long long* p) {
    return __hip_atomic_load(p, __ATOMIC_RELAXED, __HIP_MEMORY_SCOPE_AGENT);
}
static __device__ __forceinline__ void astore_u32(unsigned int* p, unsigned int v) {
    __hip_atomic_store(p, v, __ATOMIC_RELAXED, __HIP_MEMORY_SCOPE_AGENT);
}
static __device__ __forceinline__ void astore_u64(unsigned long long* p, unsigned long long v) {
    __hip_atomic_store(p, v, __ATOMIC_RELAXED, __HIP_MEMORY_SCOPE_AGENT);
}

// Gumbel exact eval: g = x*inv_t - log(-log u). Winner's u is ~1, where
// log1pf on the Sterbenz-exact (1-u) keeps relative accuracy.
static __device__ __forceinline__ float gumbel_exact(float x, float inv_t, float uu, float wm) {
    const float q = (uu > 0.984375f) ? -log1pf(-wm) : -__logf(uu);
    return x * inv_t - __logf(q);
}

// Provable upper bound of g*log2e: -log2(-log u) <= -log2(1-u) <= 127 - bits(1-u)*2^-23
static __device__ __forceinline__ float gub_bound(float a, float uu) {
    return fmaf((float)__float_as_uint(1.0f - uu), -0x1p-23f, 127.0f + a);
}

__global__ __launch_bounds__(256, 4) void k1_fused(
        const float* __restrict__ logits, const float* __restrict__ u,
        const float* __restrict__ temp,
        unsigned int* wrec,      // per-wave {s, gval, gcol, pad}  (cross-block comm)
        unsigned int* cntbuf,    // per-block raw candidate count
        uint2* candbuf,          // per-block CPB {val_bits, col}
        unsigned int* rowcnt,    // per-row arrival counter (memset to 0 pre-launch)
        float* __restrict__ out,
        int B, int V, int K, int nsplit) {
    __shared__ int cnt;
    __shared__ uint2 cand[CPB];
    __shared__ unsigned long long kbuf[512];
    __shared__ int lastflag;
    const int b = blockIdx.x;
    const int t = threadIdx.x;
    const int lane = t & 63;
    const int w = t >> 6;
    if (t == 0) cnt = 0;
    __syncthreads();

    // ---- block -> (row, split) remap: mixes greedy(r%4==0)/non-greedy rows
    // across any plausible dispatch stride. Bijective (see round-1 notes).
    const int nrows = gridDim.x / nsplit;
    const int mb = b % nrows;
    const int sp = b / nrows;
    int r = (mb * 61 + (sp >> 1)) % nrows;
    if ((nrows & (nrows - 1)) == 0) r ^= (r >> 4);
    const int slot = r * nsplit + sp;         // storage slot

    const float traw = temp[r];
    const bool greedy = traw < SAMPLING_EPS;
    const float inv_t = greedy ? 1.0f : (1.0f / traw);
    const float it2 = inv_t * LOG2E;          // scaled-arg in log2 units

    const int nf4 = V >> 2;
    const int per = (nf4 + nsplit - 1) / nsplit;
    const int f0 = sp * per;
    const int f1 = min(f0 + per, nf4);

    const float4* __restrict__ l4 = (const float4*)(logits + (size_t)r * V);
    const float4* __restrict__ u4 = (const float4*)(u + (size_t)r * V);

    float s0 = 0.0f, s1 = 0.0f, s2 = 0.0f, s3 = 0.0f;
    float gv = -INFINITY;
    int gcol = 0;
    const float4 z4 = make_float4(0.f, 0.f, 0.f, 0.f);

#define PUSH(xv, cc) do { \
        const int pi_ = atomicAdd(&cnt, 1); \
        if (pi_ < CPB) cand[pi_] = make_uint2(__float_as_uint(xv), (unsigned)(cc)); \
    } while (0)

    if (greedy) {
        int f = f0 + t;
        bool m = (f + 256 < f1);
        float4 ca = z4, cb = z4;
        if (m) { ca = l4[f]; cb = l4[f + 256]; }
        while (m) {
            const int fn = f + 512;
            const bool mn = (fn + 256 < f1);
            float4 na = z4, nb = z4;
            if (mn) { na = l4[fn]; nb = l4[fn + 256]; }
            s0 += fexp2(ca.x * it2); s1 += fexp2(ca.y * it2);
            s2 += fexp2(ca.z * it2); s3 += fexp2(ca.w * it2);
            s0 += fexp2(cb.x * it2); s1 += fexp2(cb.y * it2);
            s2 += fexp2(cb.z * it2); s3 += fexp2(cb.w * it2);
            const float xm = fmaxf(fmaxf(fmaxf(ca.x, ca.y), fmaxf(ca.z, ca.w)),
                                   fmaxf(fmaxf(cb.x, cb.y), fmaxf(cb.z, cb.w)));
            if (xm >= TAU) {
                const int c0 = f << 2, c1 = (f + 256) << 2;
                if (ca.x >= TAU) PUSH(ca.x, c0);
                if (ca.y >= TAU) PUSH(ca.y, c0 + 1);
                if (ca.z >= TAU) PUSH(ca.z, c0 + 2);
                if (ca.w >= TAU) PUSH(ca.w, c0 + 3);
                if (cb.x >= TAU) PUSH(cb.x, c1);
                if (cb.y >= TAU) PUSH(cb.y, c1 + 1);
                if (cb.z >= TAU) PUSH(cb.z, c1 + 2);
                if (cb.w >= TAU) PUSH(cb.w, c1 + 3);
            }
            f = fn; m = mn; ca = na; cb = nb;
        }
        for (; f < f1; f += 256) {
            const float4 la = l4[f];
            s0 += fexp2(la.x * it2); s1 += fexp2(la.y * it2);
            s2 += fexp2(la.z * it2); s3 += fexp2(la.w * it2);
            const float xm = fmaxf(fmaxf(la.x, la.y), fmaxf(la.z, la.w));
            if (xm >= TAU) {
                const int c0 = f << 2;
                if (la.x >= TAU) PUSH(la.x, c0);
                if (la.y >= TAU) PUSH(la.y, c0 + 1);
                if (la.z >= TAU) PUSH(la.z, c0 + 2);
                if (la.w >= TAU) PUSH(la.w, c0 + 3);
            }
        }
    } else {
        const int fp = f0 + t;
        float4 la0 = z4, ua0 = z4;
        const bool hasp = fp < f1;
        if (hasp) { la0 = l4[fp]; ua0 = u4[fp]; }
        int f = fp + 256;
        bool m = (f + 256 < f1);
        float4 ca = z4, cb = z4, cua = z4, cub = z4;
        if (m) { ca = l4[f]; cb = l4[f + 256]; cua = u4[f]; cub = u4[f + 256]; }

        if (hasp) {
            const int c0 = fp << 2;
            s0 += fexp2(la0.x * it2); s1 += fexp2(la0.y * it2);
            s2 += fexp2(la0.z * it2); s3 += fexp2(la0.w * it2);
            { const float g = gumbel_exact(la0.x, inv_t, ua0.x, 1.0f - ua0.x);
              if (g > gv) { gv = g; gcol = c0; } }
            { const float g = gumbel_exact(la0.y, inv_t, ua0.y, 1.0f - ua0.y);
              if (g > gv) { gv = g; gcol = c0 + 1; } }
            { const float g = gumbel_exact(la0.z, inv_t, ua0.z, 1.0f - ua0.z);
              if (g > gv) { gv = g; gcol = c0 + 2; } }
            { const float g = gumbel_exact(la0.w, inv_t, ua0.w, 1.0f - ua0.w);
              if (g > gv) { gv = g; gcol = c0 + 3; } }
            const float xm = fmaxf(fmaxf(la0.x, la0.y), fmaxf(la0.z, la0.w));
            if (xm >= TAU) {
                if (la0.x >= TAU) PUSH(la0.x, c0);
                if (la0.y >= TAU) PUSH(la0.y, c0 + 1);
                if (la0.z >= TAU) PUSH(la0.z, c0 + 2);
                if (la0.w >= TAU) PUSH(la0.w, c0 + 3);
            }
        }
        float gmax = gv;
        #pragma unroll
        for (int off = 1; off < 64; off <<= 1) gmax = fmaxf(gmax, __shfl_xor(gmax, off, 64));
        float gvs2 = fmaf(gmax, LOG2E, -SMARGIN);

#define EX(gj, xv, uu, cc) \
        if ((gj) > gvs2) { \
            const float wm_ = 1.0f - (uu); \
            const float ge_ = gumbel_exact(xv, inv_t, uu, wm_); \
            if (ge_ > gv) { gv = ge_; gcol = (cc); gvs2 = fmaf(ge_, LOG2E, -SMARGIN); } \
        }

        while (m) {
            const int fn = f + 512;
            const bool mn = (fn + 256 < f1);
            float4 na = z4, nb = z4, nua = z4, nub = z4;
            if (mn) { na = l4[fn]; nb = l4[fn + 256]; nua = u4[fn]; nub = u4[fn + 256]; }

            const float a0 = ca.x * it2, a1 = ca.y * it2, a2 = ca.z * it2, a3 = ca.w * it2;
            const float a4 = cb.x * it2, a5 = cb.y * it2, a6 = cb.z * it2, a7 = cb.w * it2;
            s0 += fexp2(a0); s1 += fexp2(a1); s2 += fexp2(a2); s3 += fexp2(a3);
            s0 += fexp2(a4); s1 += fexp2(a5); s2 += fexp2(a6); s3 += fexp2(a7);
            const float g0 = gub_bound(a0, cua.x), g1 = gub_bound(a1, cua.y);
            const float g2 = gub_bound(a2, cua.z), g3 = gub_bound(a3, cua.w);
            const float g4 = gub_bound(a4, cub.x), g5 = gub_bound(a5, cub.y);
            const float g6 = gub_bound(a6, cub.z), g7 = gub_bound(a7, cub.w);
            const float gm = fmaxf(fmaxf(fmaxf(g0, g1), fmaxf(g2, g3)),
                                   fmaxf(fmaxf(g4, g5), fmaxf(g6, g7)));
            if (gm > gvs2) {
                const int c0 = f << 2, c1 = (f + 256) << 2;
                EX(g0, ca.x, cua.x, c0)
                EX(g1, ca.y, cua.y, c0 + 1)
                EX(g2, ca.z, cua.z, c0 + 2)
                EX(g3, ca.w, cua.w, c0 + 3)
                EX(g4, cb.x, cub.x, c1)
                EX(g5, cb.y, cub.y, c1 + 1)
                EX(g6, cb.z, cub.z, c1 + 2)
                EX(g7, cb.w, cub.w, c1 + 3)
            }
            const float xm = fmaxf(fmaxf(fmaxf(ca.x, ca.y), fmaxf(ca.z, ca.w)),
                                   fmaxf(fmaxf(cb.x, cb.y), fmaxf(cb.z, cb.w)));
            if (xm >= TAU) {
                const int c0 = f << 2, c1 = (f + 256) << 2;
                if (ca.x >= TAU) PUSH(ca.x, c0);
                if (ca.y >= TAU) PUSH(ca.y, c0 + 1);
                if (ca.z >= TAU) PUSH(ca.z, c0 + 2);
                if (ca.w >= TAU) PUSH(ca.w, c0 + 3);
                if (cb.x >= TAU) PUSH(cb.x, c1);
                if (cb.y >= TAU) PUSH(cb.y, c1 + 1);
                if (cb.z >= TAU) PUSH(cb.z, c1 + 2);
                if (cb.w >= TAU) PUSH(cb.w, c1 + 3);
            }
            f = fn; m = mn;
            ca = na; cb = nb; cua = nua; cub = nub;
        }
        for (; f < f1; f += 256) {
            const float4 la = l4[f];
            const float4 ua = u4[f];
            const float a0 = la.x * it2, a1 = la.y * it2, a2 = la.z * it2, a3 = la.w * it2;
            s0 += fexp2(a0); s1 += fexp2(a1); s2 += fexp2(a2); s3 += fexp2(a3);
            const float g0 = gub_bound(a0, ua.x), g1 = gub_bound(a1, ua.y);
            const float g2 = gub_bound(a2, ua.z), g3 = gub_bound(a3, ua.w);
            const float gm = fmaxf(fmaxf(g0, g1), fmaxf(g2, g3));
            if (gm > gvs2) {
                const int c0 = f << 2;
                EX(g0, la.x, ua.x, c0)
                EX(g1, la.y, ua.y, c0 + 1)
                EX(g2, la.z, ua.z, c0 + 2)
                EX(g3, la.w, ua.w, c0 + 3)
            }
            const float xm = fmaxf(fmaxf(la.x, la.y), fmaxf(la.z, la.w));
            if (xm >= TAU) {
                const int c0 = f << 2;
                if (la.x >= TAU) PUSH(la.x, c0);
                if (la.y >= TAU) PUSH(la.y, c0 + 1);
                if (la.z >= TAU) PUSH(la.z, c0 + 2);
                if (la.w >= TAU) PUSH(la.w, c0 + 3);
            }
        }
#undef EX
    }
#undef PUSH

    // wave reductions: s sum, gumbel key max (val desc, col asc)
    float s = (s0 + s1) + (s2 + s3);
    #pragma unroll
    for (int off = 1; off < 64; off <<= 1) s += __shfl_xor(s, off, 64);
    unsigned long long gk = greedy ? 0ull
        : (((unsigned long long)ord32(gv) << 32) | (unsigned int)~(unsigned int)gcol);
    #pragma unroll
    for (int off = 1; off < 64; off <<= 1) {
        const unsigned long long o = shflxor64(gk, off);
        gk = (o > gk) ? o : gk;
    }
    // ---- publish partials via relaxed agent atomics (sc1, fence-free) ----
    if (lane == 0) {
        unsigned int* rp = wrec + (size_t)(slot * 4 + w) * 4;
        astore_u32(rp + 0, __float_as_uint(s));
        astore_u32(rp + 1, __float_as_uint(unord32((unsigned int)(gk >> 32))));
        astore_u32(rp + 2, ~(unsigned int)gk);
    }
    __syncthreads();
    const int c = cnt;
    if (t == 0) astore_u32(&cntbuf[slot], (unsigned)c);
    if (t < min(c, CPB)) {
        const uint2 e = cand[t];
        astore_u64((unsigned long long*)(candbuf + (size_t)slot * CPB + t),
                   ((unsigned long long)e.y << 32) | e.x);
    }

    // ================= last-block-per-row inline finalize =================
    // ensure THIS wave's sc1 stores completed (reached agent coherence point)
    asm volatile("s_waitcnt vmcnt(0)" ::: "memory");
    __syncthreads();                 // all waves' stores completed
    if (t == 0) {
        const unsigned int old = __hip_atomic_fetch_add(
            &rowcnt[r], 1u, __ATOMIC_RELAXED, __HIP_MEMORY_SCOPE_AGENT);
        lastflag = (old == (unsigned)(nsplit - 1)) ? 1 : 0;
    }
    __syncthreads();
    if (!lastflag || w != 0) return; // only wave 0 of the row-final block continues

    const int NW = nsplit * 4;
    const float tt = greedy ? 1.0f : traw;

    // merge per-wave records (relaxed agent loads; sc1 bypasses stale L2)
    float fs = 0.0f;
    unsigned long long fgk = 0ull;
    if (lane < NW) {
        const unsigned int* rp = wrec + (size_t)(r * NW + lane) * 4;
        const unsigned int a0 = aload_u32(rp + 0);
        const unsigned int a1 = aload_u32(rp + 1);
        const unsigned int a2 = aload_u32(rp + 2);
        fs = __uint_as_float(a0);
        fgk = ((unsigned long long)ord32(__uint_as_float(a1)) << 32) | (unsigned int)~a2;
    }
    #pragma unroll
    for (int off = 1; off < 64; off <<= 1) fs += __shfl_xor(fs, off, 64);
    #pragma unroll
    for (int off = 1; off < 64; off <<= 1) {
        const unsigned long long o = shflxor64(fgk, off);
        fgk = (o > fgk) ? o : fgk;
    }
    const float lS = logf(fs);

    // gather candidates
    const int cnt_raw = (lane < nsplit) ? (int)aload_u32(&cntbuf[r * nsplit + lane]) : 0;
    const int cntc = min(cnt_raw, CPB);
    const bool ovf = __ballot(cnt_raw > CPB) != 0ull;
    int incl = cntc;
    #pragma unroll
    for (int d = 1; d < 64; d <<= 1) {
        const int o = __shfl_up(incl, d, 64);
        if (lane >= d) incl += o;
    }
    const int T = __shfl(incl, 63, 64);
    const int off0 = incl - cntc;

    unsigned long long keys[8];
    #pragma unroll
    for (int jj = 0; jj < 8; ++jj) keys[jj] = 0ull;

    if (!ovf && T >= K && T <= 512) {
        if (lane < nsplit) {
            const unsigned long long* cb =
                (const unsigned long long*)(candbuf + (size_t)(r * nsplit + lane) * CPB);
            for (int i = 0; i < cntc; ++i) {
                const unsigned long long e = aload_u64(cb + i);   // lo=val_bits, hi=col
                const unsigned int vbits = (unsigned int)e;
                const unsigned int col   = (unsigned int)(e >> 32);
                kbuf[off0 + i] = ((unsigned long long)ord32(__uint_as_float(vbits)) << 32)
                               | (unsigned int)~col;
            }
        }
        __threadfence_block();   // LDS write->read ordering within the wave
        #pragma unroll
        for (int jj = 0; jj < 8; ++jj) {
            const int idx = lane + 64 * jj;
            if (idx < T) keys[jj] = kbuf[idx];
        }
    } else {
        // exact fallback: wave-cooperative top-K full rescan (insurance)
        unsigned long long mykey = ((unsigned long long)0x007FFFFFu) << 32;
        unsigned long long minkey = mykey;
        float vmin = -INFINITY;
        const float* lr = logits + (size_t)r * V;
        for (int base = 0; base < V; base += 64) {
            const int i = base + lane;
            const float x = (i < V) ? lr[i] : -INFINITY;
            unsigned long long cm = __ballot((i < V) && (x >= vmin));
            while (cm) {
                const int src = (int)__builtin_ctzll(cm);
                cm &= cm - 1;
                const float cv = __shfl(x, src, 64);
                const int cc = __shfl(i, src, 64);
                const unsigned long long ck =
                    ((unsigned long long)ord32(cv) << 32) | (unsigned int)~(unsigned int)cc;
                if (ck > minkey) {
                    const bool own = (lane < K) && (mykey == minkey);
                    const unsigned long long om = __ballot(own);
                    if (lane == (int)__builtin_ctzll(om)) mykey = ck;
                    unsigned long long mk = (lane < K) ? mykey : ~0ull;
                    #pragma unroll
                    for (int o2 = 1; o2 < 64; o2 <<= 1) {
                        const unsigned long long o = shflxor64(mk, o2);
                        mk = (o < mk) ? o : mk;
                    }
                    minkey = mk;
                    vmin = unord32((unsigned int)(mk >> 32));
                }
            }
        }
        keys[0] = (lane < K) ? mykey : 0ull;
    }

    float* out_s  = out;
    float* out_lp = out + B;
    float* out_ix = out + B + (size_t)B * K;

    unsigned int top1 = 0;
    for (int k = 0; k < K; ++k) {
        unsigned long long loc = keys[0];
        #pragma unroll
        for (int jj = 1; jj < 8; ++jj) loc = (keys[jj] > loc) ? keys[jj] : loc;
        #pragma unroll
        for (int off = 1; off < 64; off <<= 1) {
            const unsigned long long o = shflxor64(loc, off);
            loc = (o > loc) ? o : loc;
        }
        #pragma unroll
        for (int jj = 0; jj < 8; ++jj) if (keys[jj] == loc) keys[jj] = 0ull;
        if (lane == 0) {
            const unsigned int col = ~(unsigned int)loc;
            const float v = unord32((unsigned int)(loc >> 32));
            out_lp[(size_t)r * K + k] = v / tt - lS;   // IEEE div matches ref's scaled
            out_ix[(size_t)r * K + k] = (float)col;
            if (k == 0) top1 = col;
        }
    }
    if (lane == 0) {
        out_s[r] = (float)(greedy ? top1 : (~(unsigned int)fgk));
    }
}

extern "C" void kernel_launch(void* const* d_in, const int* in_sizes, int n_in,
                              void* d_out, int out_size, void* d_ws, size_t ws_size,
                              hipStream_t stream) {
    const float* logits = (const float*)d_in[0];
    const float* temp   = (const float*)d_in[1];
    const float* u      = (const float*)d_in[2];
    const int B = in_sizes[1];
    const int V = in_sizes[0] / B;
    int K = (out_size - B) / (2 * B);
    if (K > KMAX) K = KMAX;
    if (K < 1) K = 1;

    // footprint per block: wrec 4 waves*16B + cnt 4B + cand CPB*8B = 580 B, + rowcnt B*4
    int nsplit = 16;
    while (nsplit > 1 && ((size_t)B * nsplit * 580 + (size_t)B * 4) > ws_size) nsplit >>= 1;
    const int blocks = B * nsplit;

    unsigned int* wrec   = (unsigned int*)d_ws;              // blocks*4 waves * 4 u32
    unsigned int* cntbuf = wrec + (size_t)blocks * 16;       // blocks u32
    uint2*        candbf = (uint2*)(cntbuf + blocks);        // blocks * CPB uint2
    unsigned int* rowcnt = (unsigned int*)(candbf + (size_t)blocks * CPB);  // B u32

    hipMemsetAsync((void*)rowcnt, 0, (size_t)B * sizeof(unsigned int), stream);

    k1_fused<<<dim3(blocks), dim3(256), 0, stream>>>(
        logits, u, temp, wrec, cntbuf, candbf, rowcnt, (float*)d_out, B, V, K, nsplit);
}

// Round 9
// 161.803 us; speedup vs baseline: 2.3420x; 1.0203x over previous
//
#include <hip/hip_runtime.h>
#include <stdint.h>

// Sampler: B=128 rows, V=128000 vocab, K=20.
// Outputs (float32, concat): sampled[B], topk_logprobs[B*K], topk_indices[B*K].
//
// k1 (B*nsplit blocks x 256): streamed 2x-unrolled float4 with NON-TEMPORAL
//     loads (nt bit: no-allocate/evict-first in L2/MALL -- the streams have
//     zero reuse; default allocation policy measured as a ~2.5 TB/s wall
//     across 6 structural variants, R0-R7). Loads go through a native
//     ext_vector_type(4) pointer (the builtin rejects HIP_vector_type).
//     Per-lane raw exp2-sum; gumbel argmax with octet-coalesced cheap
//     screen; top-K via TAU=3.0 LDS push. Block->(row,split) remap mixes
//     greedy/non-greedy rows per CU.
// k2 (B blocks x 64): merges wave records, exact top-K among candidates;
//     exact full-rescan fallback if any row has <K candidates or overflow.

#define KMAX 20
#define SAMPLING_EPS 1e-5f
#define TAU 3.0f
#define CPB 64    // candidate slots per k1 block
#define LOG2E 1.44269504f
#define SMARGIN 3e-4f   // screen margin, log2 units (covers all fp rounding)

typedef float fx4 __attribute__((ext_vector_type(4)));

static __device__ __forceinline__ float fexp2(float x) {
#if __has_builtin(__builtin_amdgcn_exp2f)
    return __builtin_amdgcn_exp2f(x);
#else
    return exp2f(x);
#endif
}

// non-temporal 16B load: sets nt bit -> no-allocate/evict-first in cache.
// Must go through a native clang vector type (not HIP_vector_type).
static __device__ __forceinline__ float4 ntload4(const float4* p) {
#if __has_builtin(__builtin_nontemporal_load)
    const fx4 v = __builtin_nontemporal_load((const fx4*)p);
    return make_float4(v.x, v.y, v.z, v.w);
#else
    return *p;
#endif
}

static __device__ __forceinline__ unsigned int ord32(float v) {
    unsigned int u = __float_as_uint(v);
    return u ^ ((unsigned int)((int)u >> 31) | 0x80000000u);
}
static __device__ __forceinline__ float unord32(unsigned int x) {
    unsigned int u = (x & 0x80000000u) ? (x ^ 0x80000000u) : ~x;
    return __uint_as_float(u);
}
static __device__ __forceinline__ unsigned long long shflxor64(unsigned long long v, int off) {
    int lo = __shfl_xor((int)(unsigned int)v, off, 64);
    int hi = __shfl_xor((int)(unsigned int)(v >> 32), off, 64);
    return ((unsigned long long)(unsigned int)hi << 32) | (unsigned int)lo;
}

// Gumbel exact eval: g = x*inv_t - log(-log u). Winner's u is ~1, where
// log1pf on the Sterbenz-exact (1-u) keeps relative accuracy.
static __device__ __forceinline__ float gumbel_exact(float x, float inv_t, float uu, float wm) {
    const float q = (uu > 0.984375f) ? -log1pf(-wm) : -__logf(uu);
    return x * inv_t - __logf(q);
}

// Provable upper bound of g*log2e: -log2(-log u) <= -log2(1-u) <= 127 - bits(1-u)*2^-23
static __device__ __forceinline__ float gub_bound(float a, float uu) {
    return fmaf((float)__float_as_uint(1.0f - uu), -0x1p-23f, 127.0f + a);
}

__global__ __launch_bounds__(256, 4) void k1_partials(
        const float* __restrict__ logits, const float* __restrict__ u,
        const float* __restrict__ temp,
        unsigned int* __restrict__ wrec,     // per-wave {s, gval, gcol, pad}
        unsigned int* __restrict__ cntbuf,   // per-block raw candidate count
        uint2* __restrict__ candbuf,         // per-block CPB {val_bits, col}
        int V, int nsplit) {
    __shared__ int cnt;
    __shared__ uint2 cand[CPB];
    const int b = blockIdx.x;
    const int t = threadIdx.x;
    const int lane = t & 63;
    const int w = t >> 6;
    if (t == 0) cnt = 0;
    __syncthreads();

    // ---- block -> (row, split) remap: mixes greedy(r%4==0)/non-greedy rows
    // across any plausible dispatch stride. Bijective (see round-1 notes).
    const int nrows = gridDim.x / nsplit;
    const int mb = b % nrows;
    const int sp = b / nrows;
    int r = (mb * 61 + (sp >> 1)) % nrows;
    if ((nrows & (nrows - 1)) == 0) r ^= (r >> 4);
    const int slot = r * nsplit + sp;         // storage slot (k2 layout)

    const float traw = temp[r];
    const bool greedy = traw < SAMPLING_EPS;
    const float inv_t = greedy ? 1.0f : (1.0f / traw);
    const float it2 = inv_t * LOG2E;          // scaled-arg in log2 units

    const int nf4 = V >> 2;
    const int per = (nf4 + nsplit - 1) / nsplit;
    const int f0 = sp * per;
    const int f1 = min(f0 + per, nf4);

    const float4* __restrict__ l4 = (const float4*)(logits + (size_t)r * V);
    const float4* __restrict__ u4 = (const float4*)(u + (size_t)r * V);

    float s0 = 0.0f, s1 = 0.0f, s2 = 0.0f, s3 = 0.0f;
    float gv = -INFINITY;
    int gcol = 0;
    const float4 z4 = make_float4(0.f, 0.f, 0.f, 0.f);

#define PUSH(xv, cc) do { \
        const int pi_ = atomicAdd(&cnt, 1); \
        if (pi_ < CPB) cand[pi_] = make_uint2(__float_as_uint(xv), (unsigned)(cc)); \
    } while (0)

    if (greedy) {
        int f = f0 + t;
        bool m = (f + 256 < f1);
        float4 ca = z4, cb = z4;
        if (m) { ca = ntload4(l4 + f); cb = ntload4(l4 + f + 256); }
        while (m) {
            const int fn = f + 512;
            const bool mn = (fn + 256 < f1);
            float4 na = z4, nb = z4;
            if (mn) { na = ntload4(l4 + fn); nb = ntload4(l4 + fn + 256); }
            s0 += fexp2(ca.x * it2); s1 += fexp2(ca.y * it2);
            s2 += fexp2(ca.z * it2); s3 += fexp2(ca.w * it2);
            s0 += fexp2(cb.x * it2); s1 += fexp2(cb.y * it2);
            s2 += fexp2(cb.z * it2); s3 += fexp2(cb.w * it2);
            const float xm = fmaxf(fmaxf(fmaxf(ca.x, ca.y), fmaxf(ca.z, ca.w)),
                                   fmaxf(fmaxf(cb.x, cb.y), fmaxf(cb.z, cb.w)));
            if (xm >= TAU) {
                const int c0 = f << 2, c1 = (f + 256) << 2;
                if (ca.x >= TAU) PUSH(ca.x, c0);
                if (ca.y >= TAU) PUSH(ca.y, c0 + 1);
                if (ca.z >= TAU) PUSH(ca.z, c0 + 2);
                if (ca.w >= TAU) PUSH(ca.w, c0 + 3);
                if (cb.x >= TAU) PUSH(cb.x, c1);
                if (cb.y >= TAU) PUSH(cb.y, c1 + 1);
                if (cb.z >= TAU) PUSH(cb.z, c1 + 2);
                if (cb.w >= TAU) PUSH(cb.w, c1 + 3);
            }
            f = fn; m = mn; ca = na; cb = nb;
        }
        for (; f < f1; f += 256) {
            const float4 la = ntload4(l4 + f);
            s0 += fexp2(la.x * it2); s1 += fexp2(la.y * it2);
            s2 += fexp2(la.z * it2); s3 += fexp2(la.w * it2);
            const float xm = fmaxf(fmaxf(la.x, la.y), fmaxf(la.z, la.w));
            if (xm >= TAU) {
                const int c0 = f << 2;
                if (la.x >= TAU) PUSH(la.x, c0);
                if (la.y >= TAU) PUSH(la.y, c0 + 1);
                if (la.z >= TAU) PUSH(la.z, c0 + 2);
                if (la.w >= TAU) PUSH(la.w, c0 + 3);
            }
        }
    } else {
        const int fp = f0 + t;
        float4 la0 = z4, ua0 = z4;
        const bool hasp = fp < f1;
        if (hasp) { la0 = ntload4(l4 + fp); ua0 = ntload4(u4 + fp); }
        int f = fp + 256;
        bool m = (f + 256 < f1);
        float4 ca = z4, cb = z4, cua = z4, cub = z4;
        if (m) {
            ca = ntload4(l4 + f); cb = ntload4(l4 + f + 256);
            cua = ntload4(u4 + f); cub = ntload4(u4 + f + 256);
        }

        if (hasp) {
            const int c0 = fp << 2;
            s0 += fexp2(la0.x * it2); s1 += fexp2(la0.y * it2);
            s2 += fexp2(la0.z * it2); s3 += fexp2(la0.w * it2);
            { const float g = gumbel_exact(la0.x, inv_t, ua0.x, 1.0f - ua0.x);
              if (g > gv) { gv = g; gcol = c0; } }
            { const float g = gumbel_exact(la0.y, inv_t, ua0.y, 1.0f - ua0.y);
              if (g > gv) { gv = g; gcol = c0 + 1; } }
            { const float g = gumbel_exact(la0.z, inv_t, ua0.z, 1.0f - ua0.z);
              if (g > gv) { gv = g; gcol = c0 + 2; } }
            { const float g = gumbel_exact(la0.w, inv_t, ua0.w, 1.0f - ua0.w);
              if (g > gv) { gv = g; gcol = c0 + 3; } }
            const float xm = fmaxf(fmaxf(la0.x, la0.y), fmaxf(la0.z, la0.w));
            if (xm >= TAU) {
                if (la0.x >= TAU) PUSH(la0.x, c0);
                if (la0.y >= TAU) PUSH(la0.y, c0 + 1);
                if (la0.z >= TAU) PUSH(la0.z, c0 + 2);
                if (la0.w >= TAU) PUSH(la0.w, c0 + 3);
            }
        }
        float gmax = gv;
        #pragma unroll
        for (int off = 1; off < 64; off <<= 1) gmax = fmaxf(gmax, __shfl_xor(gmax, off, 64));
        float gvs2 = fmaf(gmax, LOG2E, -SMARGIN);

#define EX(gj, xv, uu, cc) \
        if ((gj) > gvs2) { \
            const float wm_ = 1.0f - (uu); \
            const float ge_ = gumbel_exact(xv, inv_t, uu, wm_); \
            if (ge_ > gv) { gv = ge_; gcol = (cc); gvs2 = fmaf(ge_, LOG2E, -SMARGIN); } \
        }

        while (m) {
            const int fn = f + 512;
            const bool mn = (fn + 256 < f1);
            float4 na = z4, nb = z4, nua = z4, nub = z4;
            if (mn) {
                na = ntload4(l4 + fn); nb = ntload4(l4 + fn + 256);
                nua = ntload4(u4 + fn); nub = ntload4(u4 + fn + 256);
            }

            const float a0 = ca.x * it2, a1 = ca.y * it2, a2 = ca.z * it2, a3 = ca.w * it2;
            const float a4 = cb.x * it2, a5 = cb.y * it2, a6 = cb.z * it2, a7 = cb.w * it2;
            s0 += fexp2(a0); s1 += fexp2(a1); s2 += fexp2(a2); s3 += fexp2(a3);
            s0 += fexp2(a4); s1 += fexp2(a5); s2 += fexp2(a6); s3 += fexp2(a7);
            const float g0 = gub_bound(a0, cua.x), g1 = gub_bound(a1, cua.y);
            const float g2 = gub_bound(a2, cua.z), g3 = gub_bound(a3, cua.w);
            const float g4 = gub_bound(a4, cub.x), g5 = gub_bound(a5, cub.y);
            const float g6 = gub_bound(a6, cub.z), g7 = gub_bound(a7, cub.w);
            const float gm = fmaxf(fmaxf(fmaxf(g0, g1), fmaxf(g2, g3)),
                                   fmaxf(fmaxf(g4, g5), fmaxf(g6, g7)));
            if (gm > gvs2) {
                const int c0 = f << 2, c1 = (f + 256) << 2;
                EX(g0, ca.x, cua.x, c0)
                EX(g1, ca.y, cua.y, c0 + 1)
                EX(g2, ca.z, cua.z, c0 + 2)
                EX(g3, ca.w, cua.w, c0 + 3)
                EX(g4, cb.x, cub.x, c1)
                EX(g5, cb.y, cub.y, c1 + 1)
                EX(g6, cb.z, cub.z, c1 + 2)
                EX(g7, cb.w, cub.w, c1 + 3)
            }
            const float xm = fmaxf(fmaxf(fmaxf(ca.x, ca.y), fmaxf(ca.z, ca.w)),
                                   fmaxf(fmaxf(cb.x, cb.y), fmaxf(cb.z, cb.w)));
            if (xm >= TAU) {
                const int c0 = f << 2, c1 = (f + 256) << 2;
                if (ca.x >= TAU) PUSH(ca.x, c0);
                if (ca.y >= TAU) PUSH(ca.y, c0 + 1);
                if (ca.z >= TAU) PUSH(ca.z, c0 + 2);
                if (ca.w >= TAU) PUSH(ca.w, c0 + 3);
                if (cb.x >= TAU) PUSH(cb.x, c1);
                if (cb.y >= TAU) PUSH(cb.y, c1 + 1);
                if (cb.z >= TAU) PUSH(cb.z, c1 + 2);
                if (cb.w >= TAU) PUSH(cb.w, c1 + 3);
            }
            f = fn; m = mn;
            ca = na; cb = nb; cua = nua; cub = nub;
        }
        for (; f < f1; f += 256) {
            const float4 la = ntload4(l4 + f);
            const float4 ua = ntload4(u4 + f);
            const float a0 = la.x * it2, a1 = la.y * it2, a2 = la.z * it2, a3 = la.w * it2;
            s0 += fexp2(a0); s1 += fexp2(a1); s2 += fexp2(a2); s3 += fexp2(a3);
            const float g0 = gub_bound(a0, ua.x), g1 = gub_bound(a1, ua.y);
            const float g2 = gub_bound(a2, ua.z), g3 = gub_bound(a3, ua.w);
            const float gm = fmaxf(fmaxf(g0, g1), fmaxf(g2, g3));
            if (gm > gvs2) {
                const int c0 = f << 2;
                EX(g0, la.x, ua.x, c0)
                EX(g1, la.y, ua.y, c0 + 1)
                EX(g2, la.z, ua.z, c0 + 2)
                EX(g3, la.w, ua.w, c0 + 3)
            }
            const float xm = fmaxf(fmaxf(la.x, la.y), fmaxf(la.z, la.w));
            if (xm >= TAU) {
                const int c0 = f << 2;
                if (la.x >= TAU) PUSH(la.x, c0);
                if (la.y >= TAU) PUSH(la.y, c0 + 1);
                if (la.z >= TAU) PUSH(la.z, c0 + 2);
                if (la.w >= TAU) PUSH(la.w, c0 + 3);
            }
        }
#undef EX
    }
#undef PUSH

    // wave reductions: s sum, gumbel key max (val desc, col asc)
    float s = (s0 + s1) + (s2 + s3);
    #pragma unroll
    for (int off = 1; off < 64; off <<= 1) s += __shfl_xor(s, off, 64);
    unsigned long long gk = greedy ? 0ull
        : (((unsigned long long)ord32(gv) << 32) | (unsigned int)~(unsigned int)gcol);
    #pragma unroll
    for (int off = 1; off < 64; off <<= 1) {
        const unsigned long long o = shflxor64(gk, off);
        gk = (o > gk) ? o : gk;
    }
    if (lane == 0) {
        unsigned int* rp = wrec + (size_t)(slot * 4 + w) * 4;
        rp[0] = __float_as_uint(s);
        rp[1] = __float_as_uint(unord32((unsigned int)(gk >> 32)));
        rp[2] = ~(unsigned int)gk;
    }
    __syncthreads();
    const int c = cnt;
    if (t == 0) cntbuf[slot] = (unsigned)c;
    if (t < min(c, CPB)) candbuf[(size_t)slot * CPB + t] = cand[t];
}

__global__ __launch_bounds__(64) void k2_finalize(
        const unsigned int* __restrict__ wrec, const unsigned int* __restrict__ cntbuf,
        const uint2* __restrict__ candbuf, const float* __restrict__ logits,
        const float* __restrict__ temp, float* __restrict__ out,
        int B, int V, int K, int nsplit) {
    __shared__ unsigned long long kbuf[512];
    const int r = blockIdx.x;
    const int lane = threadIdx.x;
    const int NW = nsplit * 4;

    const float traw = temp[r];
    const bool greedy = traw < SAMPLING_EPS;
    const float tt = greedy ? 1.0f : traw;

    // merge per-wave records
    float s = 0.0f;
    unsigned long long gk = 0ull;
    if (lane < NW) {
        const unsigned int* rp = wrec + (size_t)(r * NW + lane) * 4;
        s = __uint_as_float(rp[0]);
        gk = ((unsigned long long)ord32(__uint_as_float(rp[1])) << 32) | (unsigned int)~rp[2];
    }
    #pragma unroll
    for (int off = 1; off < 64; off <<= 1) s += __shfl_xor(s, off, 64);
    #pragma unroll
    for (int off = 1; off < 64; off <<= 1) {
        const unsigned long long o = shflxor64(gk, off);
        gk = (o > gk) ? o : gk;
    }
    const float lS = logf(s);

    // gather candidates
    const int cnt_raw = (lane < nsplit) ? (int)cntbuf[r * nsplit + lane] : 0;
    const int cntc = min(cnt_raw, CPB);
    const bool ovf = __ballot(cnt_raw > CPB) != 0ull;
    int incl = cntc;
    #pragma unroll
    for (int d = 1; d < 64; d <<= 1) {
        const int o = __shfl_up(incl, d, 64);
        if (lane >= d) incl += o;
    }
    const int T = __shfl(incl, 63, 64);
    const int off0 = incl - cntc;

    unsigned long long keys[8];
    #pragma unroll
    for (int jj = 0; jj < 8; ++jj) keys[jj] = 0ull;

    if (!ovf && T >= K && T <= 512) {
        if (lane < nsplit) {
            const uint2* cb = candbuf + (size_t)(r * nsplit + lane) * CPB;
            for (int i = 0; i < cntc; ++i) {
                const uint2 e = cb[i];
                kbuf[off0 + i] = ((unsigned long long)ord32(__uint_as_float(e.x)) << 32)
                               | (unsigned int)~e.y;
            }
        }
        __syncthreads();
        #pragma unroll
        for (int jj = 0; jj < 8; ++jj) {
            const int idx = lane + 64 * jj;
            if (idx < T) keys[jj] = kbuf[idx];
        }
    } else {
        // exact fallback: wave-cooperative top-K full rescan (insurance)
        unsigned long long mykey = ((unsigned long long)0x007FFFFFu) << 32;
        unsigned long long minkey = mykey;
        float vmin = -INFINITY;
        const float* lr = logits + (size_t)r * V;
        for (int base = 0; base < V; base += 64) {
            const int i = base + lane;
            const float x = (i < V) ? lr[i] : -INFINITY;
            unsigned long long cm = __ballot((i < V) && (x >= vmin));
            while (cm) {
                const int src = (int)__builtin_ctzll(cm);
                cm &= cm - 1;
                const float cv = __shfl(x, src, 64);
                const int cc = __shfl(i, src, 64);
                const unsigned long long ck =
                    ((unsigned long long)ord32(cv) << 32) | (unsigned int)~(unsigned int)cc;
                if (ck > minkey) {
                    const bool own = (lane < K) && (mykey == minkey);
                    const unsigned long long om = __ballot(own);
                    if (lane == (int)__builtin_ctzll(om)) mykey = ck;
                    unsigned long long mk = (lane < K) ? mykey : ~0ull;
                    #pragma unroll
                    for (int o2 = 1; o2 < 64; o2 <<= 1) {
                        const unsigned long long o = shflxor64(mk, o2);
                        mk = (o < mk) ? o : mk;
                    }
                    minkey = mk;
                    vmin = unord32((unsigned int)(mk >> 32));
                }
            }
        }
        keys[0] = (lane < K) ? mykey : 0ull;
    }

    float* out_s  = out;
    float* out_lp = out + B;
    float* out_ix = out + B + (size_t)B * K;

    unsigned int top1 = 0;
    for (int k = 0; k < K; ++k) {
        unsigned long long loc = keys[0];
        #pragma unroll
        for (int jj = 1; jj < 8; ++jj) loc = (keys[jj] > loc) ? keys[jj] : loc;
        #pragma unroll
        for (int off = 1; off < 64; off <<= 1) {
            const unsigned long long o = shflxor64(loc, off);
            loc = (o > loc) ? o : loc;
        }
        #pragma unroll
        for (int jj = 0; jj < 8; ++jj) if (keys[jj] == loc) keys[jj] = 0ull;
        if (lane == 0) {
            const unsigned int col = ~(unsigned int)loc;
            const float v = unord32((unsigned int)(loc >> 32));
            out_lp[(size_t)r * K + k] = v / tt - lS;   // IEEE div matches ref's scaled
            out_ix[(size_t)r * K + k] = (float)col;
            if (k == 0) top1 = col;
        }
    }
    if (lane == 0) {
        out_s[r] = (float)(greedy ? top1 : (~(unsigned int)gk));
    }
}

extern "C" void kernel_launch(void* const* d_in, const int* in_sizes, int n_in,
                              void* d_out, int out_size, void* d_ws, size_t ws_size,
                              hipStream_t stream) {
    const float* logits = (const float*)d_in[0];
    const float* temp   = (const float*)d_in[1];
    const float* u      = (const float*)d_in[2];
    const int B = in_sizes[1];
    const int V = in_sizes[0] / B;
    int K = (out_size - B) / (2 * B);
    if (K > KMAX) K = KMAX;
    if (K < 1) K = 1;

    // pick largest split count whose ws footprint fits
    // footprint per block: wrec 4 waves*16B + cnt 4B + cand CPB*8B = 580 B
    int nsplit = 16;
    while (nsplit > 1 && (size_t)B * nsplit * 580 > ws_size) nsplit >>= 1;
    const int blocks = B * nsplit;

    unsigned int* wrec   = (unsigned int*)d_ws;              // blocks*4 waves * 4 u32
    unsigned int* cntbuf = wrec + (size_t)blocks * 16;       // blocks u32
    uint2*        candbf = (uint2*)(cntbuf + blocks);        // blocks * CPB uint2

    k1_partials<<<dim3(blocks), dim3(256), 0, stream>>>(
        logits, u, temp, wrec, cntbuf, candbf, V, nsplit);
    k2_finalize<<<dim3(B), dim3(64), 0, stream>>>(
        wrec, cntbuf, candbf, logits, temp, (float*)d_out, B, V, K, nsplit);
}